// Round 22
// baseline (178.852 us; speedup 1.0000x reference)
//
#include <hip/hip_runtime.h>
#include <math.h>

#define NB 16
#define NC 512
#define NK 128
#define SP 4096   // 64*64 spatial positions

typedef __attribute__((ext_vector_type(8))) short short8;
typedef __attribute__((ext_vector_type(4))) float f32x4;

__device__ inline unsigned short f2bf(float f) {
    unsigned int u = __builtin_bit_cast(unsigned int, f);
    u += 0x7fffu + ((u >> 16) & 1u);   // RNE
    return (unsigned short)(u >> 16);
}

// v_cvt_pk_bf16_f32: packs bf16(lo) into [15:0], bf16(hi) into [31:16], RNE.
__device__ __forceinline__ unsigned int cvtpk(float lo, float hi) {
    unsigned int r;
    asm("v_cvt_pk_bf16_f32 %0, %1, %2" : "=v"(r) : "v"(lo), "v"(hi));
    return r;
}

// LDS act layout: byte(pos, iloc) = pos*256 + (G<<4) + (iloc&7)*2,
//   G = (iloc>>3) ^ (pos&7) ^ ((pos>>3)&7)
__device__ __forceinline__ int swzbyte(int pos, int iloc) {
    return pos * 256 + ((((iloc >> 3) ^ (pos & 7) ^ ((pos >> 3) & 7)) & 15) << 4) + (iloc & 7) * 2;
}

// ---------------------------------------------------------------------------
// ws layout (float offsets):
//   [0..2047] SY  [2048..4095] SX1  [4096..6143] SX2
//   [6144..22527]  sbr (2 br * 16 b * 512 c)
//   [22528..55295] wpre0 : wb pre-swizzled to per-wave B-frag order (65536 u16)
//   [55296..88063] wpre1 : wa (col-permuted) same order             (65536 u16)
//
// wpre element order: o = idx16*512 + lane*8 + el, where
//   idx16 = (ch*4 + kk)*8 + t8   (t8 = global 16-k tile = wv*4+nt)
//   k = t8*16 + (lane&15);  i = ch*128 + kk*32 + (lane>>4)*8 + el
// For wpre1 the logical column i' maps to wa column 8*(i'&63) + (i'>>6).
// ---------------------------------------------------------------------------

__global__ __launch_bounds__(256) void prep_weights(
    const float* __restrict__ wa, const float* __restrict__ wb,
    unsigned short* __restrict__ w0, unsigned short* __restrict__ w1,
    float* __restrict__ zbase) {
    int o = blockIdx.x * 256 + threadIdx.x;   // 0..65535
    if (o < 6144) zbase[o] = 0.f;             // zero SY/SX1/SX2 (replaces memset)
    int idx16 = o >> 9;
    int lane = (o >> 3) & 63;
    int el = o & 7;
    int t8 = idx16 & 7;
    int kk = (idx16 >> 3) & 3;
    int ch = idx16 >> 5;
    int k = t8 * 16 + (lane & 15);
    int i = ch * 128 + kk * 32 + (lane >> 4) * 8 + el;
    w0[o] = f2bf(wb[k * 512 + i]);
    int col1 = 8 * (i & 63) + (i >> 6);
    w1[o] = f2bf(wa[k * 512 + col1]);
}

// ---------------------------------------------------------------------------
// Conv+mean body, verified fragment math. 128-thread blocks = 2 waves.
// Wave wv owns k-half wv*64..+64 (nt=4 tiles of 16) over ALL 64 pos (pt=4):
// dup_A = 2 (A-tile LDS-read twice/block), dup_B = 1 (weights loaded once).
// acc[4][4] = 64 regs/thread.
// VIEW 0: i = c = ch*128+iloc;            act elem = x[b, c, g, h=pos]
// VIEW 1: i'= 128ch+iloc (qh=iloc>>6,w=iloc&63): x[b, 64*(2ch+qh)+g, w, h=pos]
// VIEW 2: i'= 128ch+64qh+(h); pos=cl*8+jh:       x[b, 8g+cl, 8*(2ch+qh)+jh, h]
// ---------------------------------------------------------------------------
template <int VIEW>
__device__ __forceinline__ void conv_body(
    int b, int g,
    const float* __restrict__ x, const unsigned short* __restrict__ wpre,
    const float* __restrict__ bias, float* __restrict__ Ssum,
    unsigned short* actS, float* red) {
    const int t = threadIdx.x;      // 0..127
    const int lane = t & 63;
    const int wv = t >> 6;          // wave id = k half (4 nt-tiles of 16)
    const int lr = lane & 15;
    const int lg = lane >> 4;

    f32x4 acc[4][4];
#pragma unroll
    for (int pt = 0; pt < 4; ++pt)
#pragma unroll
        for (int nt = 0; nt < 4; ++nt) acc[pt][nt] = (f32x4)(0.f);

    for (int ch = 0; ch < 4; ++ch) {
        if (ch) __syncthreads();   // prior chunk's readers done before overwrite

        // ---- stage act tile [64 pos][128 i]: 4 batches of 4 float4 loads ----
        if (VIEW <= 1) {
            const int cq = t & 15;           // col quad -> pos 4cq..+3
#pragma unroll
            for (int grp = 0; grp < 4; ++grp) {
                int rq = grp * 8 + (t >> 4);     // row quad 0..31
                f32x4 v[4];
#pragma unroll
                for (int j = 0; j < 4; ++j) {
                    int row = 4 * rq + j;
                    size_t ga;
                    if (VIEW == 0) {
                        ga = (size_t)(b * NC + ch * 128 + row) * SP + g * 64 + 4 * cq;
                    } else {
                        int qh = row >> 6, w = row & 63;
                        ga = (size_t)(b * NC + 64 * (2 * ch + qh) + g) * SP + w * 64 + 4 * cq;
                    }
                    v[j] = *(const f32x4*)(x + ga);
                }
#pragma unroll
                for (int m = 0; m < 4; ++m) {
                    int pos = 4 * cq + m;
                    uint2 u;   // 4 consecutive iloc (rows 4rq..+3) packed bf16
                    u.x = cvtpk(v[0][m], v[1][m]);
                    u.y = cvtpk(v[2][m], v[3][m]);
                    *(uint2*)((char*)actS + swzbyte(pos, 4 * rq)) = u;
                }
            }
        } else {
            const int u = t & 15;            // h quad
#pragma unroll
            for (int batch = 0; batch < 4; ++batch) {
                f32x4 v[4];
#pragma unroll
                for (int j = 0; j < 4; ++j) {
                    int r = (batch * 4 + j) * 8 + (t >> 4);  // 0..127
                    int cl = r >> 4, jh = (r >> 1) & 7, qh = r & 1;
                    size_t ga = (size_t)(b * NC + 8 * g + cl) * SP + (8 * (2 * ch + qh) + jh) * 64 + 4 * u;
                    v[j] = *(const f32x4*)(x + ga);
                }
#pragma unroll
                for (int j = 0; j < 4; ++j) {
                    int r = (batch * 4 + j) * 8 + (t >> 4);
                    int cl = r >> 4, jh = (r >> 1) & 7, qh = r & 1;
                    int pos = cl * 8 + jh;
                    int iloc = 64 * qh + 4 * u;
                    uint2 uu;
                    uu.x = cvtpk(v[j].x, v[j].y);
                    uu.y = cvtpk(v[j].z, v[j].w);
                    *(uint2*)((char*)actS + swzbyte(pos, iloc)) = uu;
                }
            }
        }
        __syncthreads();

        // ---- MFMA: A from LDS (4 pos-tiles), B from wpre (4 loads/kk) ----
#pragma unroll
        for (int kk = 0; kk < 4; ++kk) {
            const int ig = 4 * kk + lg;
            short8 bf[4];
#pragma unroll
            for (int nt = 0; nt < 4; ++nt) {
                int idx16 = (ch * 4 + kk) * 8 + wv * 4 + nt;
                bf[nt] = *(const short8*)(wpre + (size_t)idx16 * 512 + lane * 8);
            }
#pragma unroll
            for (int pt = 0; pt < 4; ++pt) {
                int prow = pt * 16 + lr;
                short8 a = *(const short8*)((const char*)actS + swzbyte(prow, ig * 8));
#pragma unroll
                for (int nt = 0; nt < 4; ++nt)
                    acc[pt][nt] = __builtin_amdgcn_mfma_f32_16x16x32_bf16(a, bf[nt], acc[pt][nt], 0, 0, 0);
            }
        }
    }

    // ---- epilogue: relu(acc+bias), sum all 64 pos; k-ranges wave-exclusive ----
#pragma unroll
    for (int nt = 0; nt < 4; ++nt) {
        int k = wv * 64 + nt * 16 + lr;
        float bv = bias[k];
        float s = 0.f;
#pragma unroll
        for (int pt = 0; pt < 4; ++pt)
#pragma unroll
            for (int rr = 0; rr < 4; ++rr)
                s += fmaxf(acc[pt][nt][rr] + bv, 0.f);
        s += __shfl_xor(s, 16);
        s += __shfl_xor(s, 32);
        if (lg == 0) red[k] = s;
    }
    __syncthreads();
    if (t < NK) atomicAdd(&Ssum[b * NK + t], red[t]);
}

// Merged conv launch, 1-D grid with b SLOWEST: bid = b*192 + view*64 + g.
// 128-thread blocks; (128,4) -> 8 blocks/CU (16 waves), VGPR cap 128.
__global__ __launch_bounds__(128, 4) void conv_all(
    const float* __restrict__ x,
    const unsigned short* __restrict__ wpre0, const unsigned short* __restrict__ wpre1,
    const float* __restrict__ bb, const float* __restrict__ ba,
    float* __restrict__ SY, float* __restrict__ SX1, float* __restrict__ SX2) {
    __shared__ __align__(16) unsigned short actS[64 * 128];   // 16 KB
    __shared__ float red[NK];
    const int bid = blockIdx.x;
    const int b = bid / 192;
    const int rem = bid - b * 192;
    const int view = rem >> 6;
    const int g = rem & 63;
    if (view == 0)      conv_body<0>(b, g, x, wpre0, bb, SY,  actS, red);
    else if (view == 1) conv_body<1>(b, g, x, wpre1, ba, SX1, actS, red);
    else                conv_body<2>(b, g, x, wpre1, ba, SX2, actS, red);
}

// Per-(b,branch) MLP chain
__global__ __launch_bounds__(256) void chain_kernel(
    const float* __restrict__ Sy, const float* __restrict__ Sx1,
    const float* __restrict__ Sx2, const float* __restrict__ wd,
    const float* __restrict__ wc1, const float* __restrict__ bc1,
    const float* __restrict__ wc2, const float* __restrict__ bc2,
    float* __restrict__ sbr) {
    __shared__ float m[128];
    __shared__ float ap[512];
    __shared__ float z[128];
    const int b = blockIdx.x, br = blockIdx.y, t = threadIdx.x;
    const float* Sx = (br == 0) ? Sx1 : Sx2;
    const float inv = 1.0f / 4096.0f;

    if (t < 128) m[t] = (Sy[b * NK + t] + Sx[b * NK + t]) * inv;
    __syncthreads();
    for (int c = t; c < NC; c += 256) {
        float v = 0.f;
        for (int k = 0; k < NK; ++k) v += wd[c * NK + k] * m[k];
        ap[c] = v;
    }
    __syncthreads();
    if (t < 128) {
        float v = bc1[t];
        for (int c = 0; c < NC; ++c) v += wc1[t * NC + c] * ap[c];
        z[t] = fmaxf(v, 0.f);
    }
    __syncthreads();
    for (int c = t; c < NC; c += 256) {
        float v = bc2[c];
        for (int k = 0; k < NK; ++k) v += wc2[c * NK + k] * z[k];
        sbr[(br * NB + b) * NC + c] = 1.f / (1.f + expf(-v));
    }
}

// out[b,c,s] = x[b,c,s] + s1[b,c] + s2[b,c]  (streaming: nontemporal x/out)
__global__ __launch_bounds__(256) void final_add(
    const float* __restrict__ x, const float* __restrict__ sbr,
    float* __restrict__ out) {
    const int total4 = NB * NC * SP / 4;   // 8388608
    for (int i = blockIdx.x * 256 + threadIdx.x; i < total4; i += gridDim.x * 256) {
        int flat = i * 4;
        int bc = flat >> 12;
        int b = bc >> 9, c = bc & 511;
        float s = sbr[b * NC + c] + sbr[NB * NC + b * NC + c];
        f32x4 xv = __builtin_nontemporal_load((const f32x4*)x + i);
        f32x4 o = {xv.x + s, xv.y + s, xv.z + s, xv.w + s};
        __builtin_nontemporal_store(o, (f32x4*)out + i);
    }
}

extern "C" void kernel_launch(void* const* d_in, const int* in_sizes, int n_in,
                              void* d_out, int out_size, void* d_ws, size_t ws_size,
                              hipStream_t stream) {
    const float* x   = (const float*)d_in[0];
    const float* wa  = (const float*)d_in[1];
    const float* ba  = (const float*)d_in[2];
    const float* wb  = (const float*)d_in[3];
    const float* bb  = (const float*)d_in[4];
    const float* wd  = (const float*)d_in[5];
    const float* wc1 = (const float*)d_in[6];
    const float* bc1 = (const float*)d_in[7];
    const float* wc2 = (const float*)d_in[8];
    const float* bc2 = (const float*)d_in[9];
    float* out = (float*)d_out;

    float* ws  = (float*)d_ws;
    float* SY  = ws;
    float* SX1 = ws + 2048;
    float* SX2 = ws + 4096;
    float* sbr = ws + 6144;
    unsigned short* wpre0 = (unsigned short*)(ws + 22528);
    unsigned short* wpre1 = (unsigned short*)(ws + 55296);

    prep_weights<<<256, 256, 0, stream>>>(wa, wb, wpre0, wpre1, ws);
    conv_all<<<dim3(192 * NB), 128, 0, stream>>>(x, wpre0, wpre1, bb, ba, SY, SX1, SX2);
    chain_kernel<<<dim3(NB, 2), 256, 0, stream>>>(SY, SX1, SX2, wd, wc1, bc1, wc2, bc2, sbr);
    final_add<<<2048, 256, 0, stream>>>(x, sbr, out);
}

// Round 23
// 134.458 us; speedup vs baseline: 1.3302x; 1.3302x over previous
//
#include <hip/hip_runtime.h>
#include <math.h>

#define NB 16
#define NC 512
#define NK 128
#define SP 4096   // 64*64 spatial positions

typedef __attribute__((ext_vector_type(8))) short short8;
typedef __attribute__((ext_vector_type(4))) float f32x4;

__device__ inline unsigned short f2bf(float f) {
    unsigned int u = __builtin_bit_cast(unsigned int, f);
    u += 0x7fffu + ((u >> 16) & 1u);   // RNE
    return (unsigned short)(u >> 16);
}

// v_cvt_pk_bf16_f32: packs bf16(lo) into [15:0], bf16(hi) into [31:16], RNE.
__device__ __forceinline__ unsigned int cvtpk(float lo, float hi) {
    unsigned int r;
    asm("v_cvt_pk_bf16_f32 %0, %1, %2" : "=v"(r) : "v"(lo), "v"(hi));
    return r;
}

// LDS act layout: byte(pos, iloc) = pos*256 + (G<<4) + (iloc&7)*2,
//   G = (iloc>>3) ^ (pos&7) ^ ((pos>>3)&7)
__device__ __forceinline__ int swzbyte(int pos, int iloc) {
    return pos * 256 + ((((iloc >> 3) ^ (pos & 7) ^ ((pos >> 3) & 7)) & 15) << 4) + (iloc & 7) * 2;
}

// ---------------------------------------------------------------------------
// ws layout (float offsets):
//   [0..2047] SY  [2048..4095] SX1  [4096..6143] SX2
//   [6144..22527]  sbr (2 br * 16 b * 512 c)
//   [22528..55295] wpre0 : wb pre-swizzled to per-wave B-frag order (65536 u16)
//   [55296..88063] wpre1 : wa (col-permuted) same order             (65536 u16)
//
// wpre element order: o = idx16*512 + lane*8 + el, where
//   idx16 = (ch*4 + kk)*8 + t8   (t8 = global 16-k tile = kq*2+nt)
//   k = t8*16 + (lane&15);  i = ch*128 + kk*32 + (lane>>4)*8 + el
// For wpre1 the logical column i' maps to wa column 8*(i'&63) + (i'>>6).
// ---------------------------------------------------------------------------

__global__ __launch_bounds__(256) void prep_weights(
    const float* __restrict__ wa, const float* __restrict__ wb,
    unsigned short* __restrict__ w0, unsigned short* __restrict__ w1,
    float* __restrict__ zbase) {
    int o = blockIdx.x * 256 + threadIdx.x;   // 0..65535
    if (o < 6144) zbase[o] = 0.f;             // zero SY/SX1/SX2 (replaces memset)
    int idx16 = o >> 9;
    int lane = (o >> 3) & 63;
    int el = o & 7;
    int t8 = idx16 & 7;
    int kk = (idx16 >> 3) & 3;
    int ch = idx16 >> 5;
    int k = t8 * 16 + (lane & 15);
    int i = ch * 128 + kk * 32 + (lane >> 4) * 8 + el;
    w0[o] = f2bf(wb[k * 512 + i]);
    int col1 = 8 * (i & 63) + (i >> 6);
    w1[o] = f2bf(wa[k * 512 + col1]);
}

// ---------------------------------------------------------------------------
// Conv+mean body, verified fragment math (r18/r19 base). Staging pack via
// v_cvt_pk_bf16_f32. 4 waves = 4 kq (nt=2 tiles of 16); each wave covers
// ALL 64 pos (pt=4) -> dup_A=4, dup_B=1 (Pareto-optimal feasible split).
// VIEW 0: i = c = ch*128+iloc;            act elem = x[b, c, g, h=pos]
// VIEW 1: i'= 128ch+iloc (qh=iloc>>6,w=iloc&63): x[b, 64*(2ch+qh)+g, w, h=pos]
// VIEW 2: i'= 128ch+64qh+(h); pos=cl*8+jh:       x[b, 8g+cl, 8*(2ch+qh)+jh, h]
// ---------------------------------------------------------------------------
template <int VIEW>
__device__ __forceinline__ void conv_body(
    int b, int g,
    const float* __restrict__ x, const unsigned short* __restrict__ wpre,
    const float* __restrict__ bias, float* __restrict__ Ssum,
    unsigned short* actS, float* red) {
    const int t = threadIdx.x;
    const int lane = t & 63;
    const int kq = t >> 6;       // wave id = k quarter (2 nt-tiles of 16)
    const int lr = lane & 15;
    const int lg = lane >> 4;

    f32x4 acc[4][2];
#pragma unroll
    for (int pt = 0; pt < 4; ++pt)
#pragma unroll
        for (int nt = 0; nt < 2; ++nt) acc[pt][nt] = (f32x4)(0.f);

    for (int ch = 0; ch < 4; ++ch) {
        if (ch) __syncthreads();   // prior chunk's readers done before overwrite

        // ---- stage act tile [64 pos][128 i]: 8 loads up-front, then writes ----
        if (VIEW <= 1) {
            const int cq = t & 15;           // col quad -> pos 4cq..+3
            f32x4 v[8];
#pragma unroll
            for (int grp = 0; grp < 2; ++grp) {
                int rq = grp * 16 + (t >> 4);    // rows 4rq..+3
#pragma unroll
                for (int j = 0; j < 4; ++j) {
                    int row = 4 * rq + j;
                    size_t ga;
                    if (VIEW == 0) {
                        ga = (size_t)(b * NC + ch * 128 + row) * SP + g * 64 + 4 * cq;
                    } else {
                        int qh = row >> 6, w = row & 63;
                        ga = (size_t)(b * NC + 64 * (2 * ch + qh) + g) * SP + w * 64 + 4 * cq;
                    }
                    v[grp * 4 + j] = *(const f32x4*)(x + ga);
                }
            }
#pragma unroll
            for (int grp = 0; grp < 2; ++grp) {
                int rq = grp * 16 + (t >> 4);
#pragma unroll
                for (int m = 0; m < 4; ++m) {
                    int pos = 4 * cq + m;
                    uint2 u;   // 4 consecutive iloc (rows 4rq..+3) as 2x packed bf16
                    u.x = cvtpk(v[grp * 4 + 0][m], v[grp * 4 + 1][m]);
                    u.y = cvtpk(v[grp * 4 + 2][m], v[grp * 4 + 3][m]);
                    *(uint2*)((char*)actS + swzbyte(pos, 4 * rq)) = u;
                }
            }
        } else {
            const int u = t & 15;            // h quad
            f32x4 v[8];
#pragma unroll
            for (int it = 0; it < 8; ++it) {
                int r = it * 16 + (t >> 4);  // 0..127
                int cl = r >> 4, jh = (r >> 1) & 7, qh = r & 1;
                size_t ga = (size_t)(b * NC + 8 * g + cl) * SP + (8 * (2 * ch + qh) + jh) * 64 + 4 * u;
                v[it] = *(const f32x4*)(x + ga);
            }
#pragma unroll
            for (int it = 0; it < 8; ++it) {
                int r = it * 16 + (t >> 4);
                int cl = r >> 4, jh = (r >> 1) & 7, qh = r & 1;
                int pos = cl * 8 + jh;
                int iloc = 64 * qh + 4 * u;
                uint2 uu;   // 4 consecutive iloc (h quad) as 2x packed bf16
                uu.x = cvtpk(v[it].x, v[it].y);
                uu.y = cvtpk(v[it].z, v[it].w);
                *(uint2*)((char*)actS + swzbyte(pos, iloc)) = uu;
            }
        }
        __syncthreads();

        // ---- MFMA: A from LDS (4 pos-tiles), B from wpre (2 loads/kk) ----
#pragma unroll
        for (int kk = 0; kk < 4; ++kk) {
            const int ig = 4 * kk + lg;
            short8 bf[2];
#pragma unroll
            for (int nt = 0; nt < 2; ++nt) {
                int idx16 = (ch * 4 + kk) * 8 + kq * 2 + nt;
                bf[nt] = *(const short8*)(wpre + (size_t)idx16 * 512 + lane * 8);
            }
#pragma unroll
            for (int pt = 0; pt < 4; ++pt) {
                int prow = pt * 16 + lr;
                short8 a = *(const short8*)((const char*)actS + swzbyte(prow, ig * 8));
#pragma unroll
                for (int nt = 0; nt < 2; ++nt)
                    acc[pt][nt] = __builtin_amdgcn_mfma_f32_16x16x32_bf16(a, bf[nt], acc[pt][nt], 0, 0, 0);
            }
        }
    }

    // ---- epilogue: relu(acc+bias), sum all 64 pos; k-ranges wave-exclusive
    // so red[] needs no atomics ----
#pragma unroll
    for (int nt = 0; nt < 2; ++nt) {
        int k = kq * 32 + nt * 16 + lr;
        float bv = bias[k];
        float s = 0.f;
#pragma unroll
        for (int pt = 0; pt < 4; ++pt)
#pragma unroll
            for (int rr = 0; rr < 4; ++rr)
                s += fmaxf(acc[pt][nt][rr] + bv, 0.f);
        s += __shfl_xor(s, 16);
        s += __shfl_xor(s, 32);
        if (lg == 0) red[k] = s;
    }
    __syncthreads();
    if (t < NK) atomicAdd(&Ssum[b * NK + t], red[t]);
}

// Merged conv launch, 1-D grid with b SLOWEST: bid = b*192 + view*64 + g.
__global__ __launch_bounds__(256, 4) void conv_all(
    const float* __restrict__ x,
    const unsigned short* __restrict__ wpre0, const unsigned short* __restrict__ wpre1,
    const float* __restrict__ bb, const float* __restrict__ ba,
    float* __restrict__ SY, float* __restrict__ SX1, float* __restrict__ SX2) {
    __shared__ __align__(16) unsigned short actS[64 * 128];   // 16 KB
    __shared__ float red[NK];
    const int bid = blockIdx.x;
    const int b = bid / 192;
    const int rem = bid - b * 192;
    const int view = rem >> 6;
    const int g = rem & 63;
    if (view == 0)      conv_body<0>(b, g, x, wpre0, bb, SY,  actS, red);
    else if (view == 1) conv_body<1>(b, g, x, wpre1, ba, SX1, actS, red);
    else                conv_body<2>(b, g, x, wpre1, ba, SX2, actS, red);
}

// Per-(b,branch) MLP chain
__global__ __launch_bounds__(256) void chain_kernel(
    const float* __restrict__ Sy, const float* __restrict__ Sx1,
    const float* __restrict__ Sx2, const float* __restrict__ wd,
    const float* __restrict__ wc1, const float* __restrict__ bc1,
    const float* __restrict__ wc2, const float* __restrict__ bc2,
    float* __restrict__ sbr) {
    __shared__ float m[128];
    __shared__ float ap[512];
    __shared__ float z[128];
    const int b = blockIdx.x, br = blockIdx.y, t = threadIdx.x;
    const float* Sx = (br == 0) ? Sx1 : Sx2;
    const float inv = 1.0f / 4096.0f;

    if (t < 128) m[t] = (Sy[b * NK + t] + Sx[b * NK + t]) * inv;
    __syncthreads();
    for (int c = t; c < NC; c += 256) {
        float v = 0.f;
        for (int k = 0; k < NK; ++k) v += wd[c * NK + k] * m[k];
        ap[c] = v;
    }
    __syncthreads();
    if (t < 128) {
        float v = bc1[t];
        for (int c = 0; c < NC; ++c) v += wc1[t * NC + c] * ap[c];
        z[t] = fmaxf(v, 0.f);
    }
    __syncthreads();
    for (int c = t; c < NC; c += 256) {
        float v = bc2[c];
        for (int k = 0; k < NK; ++k) v += wc2[c * NK + k] * z[k];
        sbr[(br * NB + b) * NC + c] = 1.f / (1.f + expf(-v));
    }
}

// out[b,c,s] = x[b,c,s] + s1[b,c] + s2[b,c]  (streaming: nontemporal x/out)
__global__ __launch_bounds__(256) void final_add(
    const float* __restrict__ x, const float* __restrict__ sbr,
    float* __restrict__ out) {
    const int total4 = NB * NC * SP / 4;   // 8388608
    for (int i = blockIdx.x * 256 + threadIdx.x; i < total4; i += gridDim.x * 256) {
        int flat = i * 4;
        int bc = flat >> 12;
        int b = bc >> 9, c = bc & 511;
        float s = sbr[b * NC + c] + sbr[NB * NC + b * NC + c];
        f32x4 xv = __builtin_nontemporal_load((const f32x4*)x + i);
        f32x4 o = {xv.x + s, xv.y + s, xv.z + s, xv.w + s};
        __builtin_nontemporal_store(o, (f32x4*)out + i);
    }
}

extern "C" void kernel_launch(void* const* d_in, const int* in_sizes, int n_in,
                              void* d_out, int out_size, void* d_ws, size_t ws_size,
                              hipStream_t stream) {
    const float* x   = (const float*)d_in[0];
    const float* wa  = (const float*)d_in[1];
    const float* ba  = (const float*)d_in[2];
    const float* wb  = (const float*)d_in[3];
    const float* bb  = (const float*)d_in[4];
    const float* wd  = (const float*)d_in[5];
    const float* wc1 = (const float*)d_in[6];
    const float* bc1 = (const float*)d_in[7];
    const float* wc2 = (const float*)d_in[8];
    const float* bc2 = (const float*)d_in[9];
    float* out = (float*)d_out;

    float* ws  = (float*)d_ws;
    float* SY  = ws;
    float* SX1 = ws + 2048;
    float* SX2 = ws + 4096;
    float* sbr = ws + 6144;
    unsigned short* wpre0 = (unsigned short*)(ws + 22528);
    unsigned short* wpre1 = (unsigned short*)(ws + 55296);

    prep_weights<<<256, 256, 0, stream>>>(wa, wb, wpre0, wpre1, ws);
    conv_all<<<dim3(192 * NB), 256, 0, stream>>>(x, wpre0, wpre1, bb, ba, SY, SX1, SX2);
    chain_kernel<<<dim3(NB, 2), 256, 0, stream>>>(SY, SX1, SX2, wd, wc1, bc1, wc2, bc2, sbr);
    final_add<<<2048, 256, 0, stream>>>(x, sbr, out);
}